// Round 4
// baseline (340.000 us; speedup 1.0000x reference)
//
#include <hip/hip_runtime.h>

#define Bn 256
#define Nn 64
#define Tn 50
#define Fn 2
#define En 64
#define Hn 128
#define Rn 30
#define G4 512   // 4*H
#define Kd 192   // xt(64) + h(128)

__device__ __forceinline__ float sigf(float x) {
    return __builtin_amdgcn_rcpf(1.0f + __expf(-x));
}
__device__ __forceinline__ float tanh_fast(float x) {
    // tanh(x) = 1 - 2/(exp(2x)+1); stable both tails in fp32
    return 1.0f - 2.0f * __builtin_amdgcn_rcpf(__expf(2.0f * x) + 1.0f);
}

// ---------------- Phase 1: emb[b*T+t, e] = relu(gcn + x@W_res) at node 0 ----------------
__global__ __launch_bounds__(256) void k_emb(const float* __restrict__ src,
                                             const float* __restrict__ W_res,
                                             const float* __restrict__ W_gcn,
                                             const float* __restrict__ b_gcn,
                                             float* __restrict__ emb)
{
    const int wave = threadIdx.x >> 6;
    const int lane = threadIdx.x & 63;
    const int task = blockIdx.x * 4 + wave;      // b*Tn + t
    const int b = task / Tn;
    const int t = task - b * Tn;

    __shared__ float2 xs[4][Nn];

    const float2 xv = *reinterpret_cast<const float2*>(
        src + (((size_t)b * Nn + lane) * Tn + t) * Fn);
    const float x0 = xv.x, x1 = xv.y;
    xs[wave][lane] = xv;
    __syncthreads();

    float rowsum = 0.0f, w0 = 0.0f;
    #pragma unroll
    for (int k = 0; k < Nn; k++) {
        const float2 o = xs[wave][k];
        const float dx = x0 - o.x, dy = x1 - o.y;
        const float w = fminf(__builtin_amdgcn_rsqf(dx * dx + dy * dy), 1.0f);
        rowsum += w;
        if (k == 0) w0 = w;
    }
    const float dinv  = __builtin_amdgcn_rsqf(rowsum);
    const float dinv0 = __shfl(dinv, 0);
    const float a = w0 * dinv0 * dinv;    // A[0, j]

    float p0 = a * x0, p1 = a * x1;
    #pragma unroll
    for (int off = 32; off; off >>= 1) {
        p0 += __shfl_xor(p0, off);
        p1 += __shfl_xor(p1, off);
    }
    const float xa = __shfl(x0, 0);
    const float xb = __shfl(x1, 0);

    const float v = p0 * W_gcn[lane] + p1 * W_gcn[En + lane] + b_gcn[lane]
                  + xa * W_res[lane] + xb * W_res[En + lane];
    emb[(size_t)task * En + lane] = fmaxf(v, 0.0f);
}

// ---------------- Phase 2+3: encoder (T) + decoder (R) LSTM ----------------
// 1024 threads / block, 1 batch element / block, 1 block / CU.
// Thread (j2 = (lane&7)+8*wv, s = lane>>3): partial gates for cell j2 over
// k-chunk [24s, 24s+24) of v = [xt(64)|h(128)]. 96 weights/thread fits the
// 128-VGPR budget that a 1024-thread block forces (R2/R3: 512 threads x 192
// weights spilled 100 MB to scratch; attributes to raise the budget were
// ignored by the backend).
__global__ __launch_bounds__(1024) void k_seq(
    const float* __restrict__ emb,
    const float* __restrict__ src,
    const float* __restrict__ W_ih_e, const float* __restrict__ W_hh_e, const float* __restrict__ b_e,
    const float* __restrict__ W1,     const float* __restrict__ b1,
    const float* __restrict__ W_ih_d, const float* __restrict__ W_hh_d, const float* __restrict__ b_d,
    const float* __restrict__ W2,     const float* __restrict__ b2,
    float* __restrict__ out)
{
    const int tid  = threadIdx.x;
    const int lane = tid & 63;
    const int wv   = tid >> 6;                 // 0..15
    const int s    = lane >> 3;                // 0..7 k-chunk
    const int j2   = (lane & 7) + (wv << 3);   // 0..127 cell index
    const int b    = blockIdx.x;

    __shared__ __align__(16) float vbuf[2][Kd];
    __shared__ float red[16][2];
    __shared__ float xin_sh[2];

    float w[96];     // w[m*24+kk] = Wcat[24s+kk][j2+128m]
    float bias[4];
    float c = 0.0f;

    // ---- encoder weights into VGPRs (one column-chunk per thread) ----
    #pragma unroll
    for (int m = 0; m < 4; m++) {
        const int col = j2 + (m << 7);
        #pragma unroll
        for (int kk = 0; kk < 24; kk++) {
            const int k = s * 24 + kk;
            const float* p = (k < En) ? (W_ih_e + (size_t)k * G4 + col)
                                      : (W_hh_e + (size_t)(k - En) * G4 + col);
            float v = *p;
            asm volatile("" : "+v"(v));
            w[m * 24 + kk] = v;
        }
        float bv = b_e[col];
        asm volatile("" : "+v"(bv));
        bias[m] = bv;
    }

    const float* emb_b = emb + (size_t)b * Tn * En;

    // init: vbuf[0] = [emb row 0 | h=0]
    if (tid < En) vbuf[0][tid] = emb_b[tid];
    if (tid < Hn) vbuf[0][En + tid] = 0.0f;
    __syncthreads();

    // ---- encoder: 50 steps, 1 barrier/step ----
    #pragma unroll 1
    for (int t = 0; t < Tn; t++) {
        const int cur = t & 1;
        float xt_next = 0.0f;
        if (tid < En && t + 1 < Tn) xt_next = emb_b[(t + 1) * En + tid];

        const float4* v4 = reinterpret_cast<const float4*>(&vbuf[cur][s * 24]);
        float a0 = 0.0f, a1 = 0.0f, a2 = 0.0f, a3 = 0.0f;
        #pragma unroll
        for (int i = 0; i < 6; i++) {
            const float4 u = v4[i];
            a0 = fmaf(u.x, w[0*24+4*i+0], a0); a0 = fmaf(u.y, w[0*24+4*i+1], a0);
            a0 = fmaf(u.z, w[0*24+4*i+2], a0); a0 = fmaf(u.w, w[0*24+4*i+3], a0);
            a1 = fmaf(u.x, w[1*24+4*i+0], a1); a1 = fmaf(u.y, w[1*24+4*i+1], a1);
            a1 = fmaf(u.z, w[1*24+4*i+2], a1); a1 = fmaf(u.w, w[1*24+4*i+3], a1);
            a2 = fmaf(u.x, w[2*24+4*i+0], a2); a2 = fmaf(u.y, w[2*24+4*i+1], a2);
            a2 = fmaf(u.z, w[2*24+4*i+2], a2); a2 = fmaf(u.w, w[2*24+4*i+3], a2);
            a3 = fmaf(u.x, w[3*24+4*i+0], a3); a3 = fmaf(u.y, w[3*24+4*i+1], a3);
            a3 = fmaf(u.z, w[3*24+4*i+2], a3); a3 = fmaf(u.w, w[3*24+4*i+3], a3);
        }
        // butterfly all-reduce over the 8 s-lanes sharing this cell
        a0 += __shfl_xor(a0, 8);  a1 += __shfl_xor(a1, 8);
        a2 += __shfl_xor(a2, 8);  a3 += __shfl_xor(a3, 8);
        a0 += __shfl_xor(a0, 16); a1 += __shfl_xor(a1, 16);
        a2 += __shfl_xor(a2, 16); a3 += __shfl_xor(a3, 16);
        a0 += __shfl_xor(a0, 32); a1 += __shfl_xor(a1, 32);
        a2 += __shfl_xor(a2, 32); a3 += __shfl_xor(a3, 32);

        const float gi = a0 + bias[0], gf = a1 + bias[1];
        const float gg = a2 + bias[2], go = a3 + bias[3];
        c = sigf(gf) * c + sigf(gi) * tanh_fast(gg);
        const float h = sigf(go) * tanh_fast(c);

        if (s == 0) vbuf[cur ^ 1][En + j2] = h;
        if (tid < En && t + 1 < Tn) vbuf[cur ^ 1][tid] = xt_next;
        __syncthreads();
    }

    // ---- decoder weights into VGPRs ----
    #pragma unroll
    for (int m = 0; m < 4; m++) {
        const int col = j2 + (m << 7);
        #pragma unroll
        for (int kk = 0; kk < 24; kk++) {
            const int k = s * 24 + kk;
            const float* p = (k < En) ? (W_ih_d + (size_t)k * G4 + col)
                                      : (W_hh_d + (size_t)(k - En) * G4 + col);
            float v = *p;
            asm volatile("" : "+v"(v));
            w[m * 24 + kk] = v;
        }
        float bv = b_d[col];
        asm volatile("" : "+v"(bv));
        bias[m] = bv;
    }
    float w1a = 0.0f, w1b = 0.0f, b1v = 0.0f;
    if (tid < En) { w1a = W1[tid]; w1b = W1[En + tid]; b1v = b1[tid]; }
    const float w2a = W2[2 * j2], w2b = W2[2 * j2 + 1];

    const float xin0 = src[(size_t)b * Nn * Tn * Fn + (Tn - 1) * Fn + 0];
    const float xin1 = src[(size_t)b * Nn * Tn * Fn + (Tn - 1) * Fn + 1];
    if (tid < En) vbuf[0][tid] = fmaxf(xin0 * w1a + xin1 * w1b + b1v, 0.0f);
    __syncthreads();

    // ---- decoder: 30 steps, 3 barriers/step ----
    #pragma unroll 1
    for (int r = 0; r < Rn; r++) {
        const int cur = r & 1;
        const float4* v4 = reinterpret_cast<const float4*>(&vbuf[cur][s * 24]);
        float a0 = 0.0f, a1 = 0.0f, a2 = 0.0f, a3 = 0.0f;
        #pragma unroll
        for (int i = 0; i < 6; i++) {
            const float4 u = v4[i];
            a0 = fmaf(u.x, w[0*24+4*i+0], a0); a0 = fmaf(u.y, w[0*24+4*i+1], a0);
            a0 = fmaf(u.z, w[0*24+4*i+2], a0); a0 = fmaf(u.w, w[0*24+4*i+3], a0);
            a1 = fmaf(u.x, w[1*24+4*i+0], a1); a1 = fmaf(u.y, w[1*24+4*i+1], a1);
            a1 = fmaf(u.z, w[1*24+4*i+2], a1); a1 = fmaf(u.w, w[1*24+4*i+3], a1);
            a2 = fmaf(u.x, w[2*24+4*i+0], a2); a2 = fmaf(u.y, w[2*24+4*i+1], a2);
            a2 = fmaf(u.z, w[2*24+4*i+2], a2); a2 = fmaf(u.w, w[2*24+4*i+3], a2);
            a3 = fmaf(u.x, w[3*24+4*i+0], a3); a3 = fmaf(u.y, w[3*24+4*i+1], a3);
            a3 = fmaf(u.z, w[3*24+4*i+2], a3); a3 = fmaf(u.w, w[3*24+4*i+3], a3);
        }
        a0 += __shfl_xor(a0, 8);  a1 += __shfl_xor(a1, 8);
        a2 += __shfl_xor(a2, 8);  a3 += __shfl_xor(a3, 8);
        a0 += __shfl_xor(a0, 16); a1 += __shfl_xor(a1, 16);
        a2 += __shfl_xor(a2, 16); a3 += __shfl_xor(a3, 16);
        a0 += __shfl_xor(a0, 32); a1 += __shfl_xor(a1, 32);
        a2 += __shfl_xor(a2, 32); a3 += __shfl_xor(a3, 32);

        const float gi = a0 + bias[0], gf = a1 + bias[1];
        const float gg = a2 + bias[2], go = a3 + bias[3];
        c = sigf(gf) * c + sigf(gi) * tanh_fast(gg);
        const float h = sigf(go) * tanh_fast(c);

        if (s == 0) vbuf[cur ^ 1][En + j2] = h;

        // out = h @ W2 + b2 (s==0 lanes contribute, 8 cells per wave)
        float p0 = (s == 0) ? h * w2a : 0.0f;
        float p1 = (s == 0) ? h * w2b : 0.0f;
        #pragma unroll
        for (int off = 32; off; off >>= 1) {
            p0 += __shfl_xor(p0, off);
            p1 += __shfl_xor(p1, off);
        }
        if (lane == 0) { red[wv][0] = p0; red[wv][1] = p1; }
        __syncthreads();

        if (tid < 2) {
            float o = b2[tid];
            #pragma unroll
            for (int k2 = 0; k2 < 16; k2++) o += red[k2][tid];
            out[((size_t)b * Rn + r) * Fn + tid] = o;
            xin_sh[tid] = o;
        }
        __syncthreads();

        if (r + 1 < Rn && tid < En) {
            vbuf[cur ^ 1][tid] = fmaxf(xin_sh[0] * w1a + xin_sh[1] * w1b + b1v, 0.0f);
        }
        __syncthreads();
    }
}

extern "C" void kernel_launch(void* const* d_in, const int* in_sizes, int n_in,
                              void* d_out, int out_size, void* d_ws, size_t ws_size,
                              hipStream_t stream)
{
    const float* src    = (const float*)d_in[0];
    const float* W_res  = (const float*)d_in[2];
    const float* W_gcn  = (const float*)d_in[3];
    const float* b_gcn  = (const float*)d_in[4];
    const float* W_ih_e = (const float*)d_in[5];
    const float* W_hh_e = (const float*)d_in[6];
    const float* b_e    = (const float*)d_in[7];
    const float* W1     = (const float*)d_in[8];
    const float* b1     = (const float*)d_in[9];
    const float* W_ih_d = (const float*)d_in[10];
    const float* W_hh_d = (const float*)d_in[11];
    const float* b_d    = (const float*)d_in[12];
    const float* W2     = (const float*)d_in[13];
    const float* b2     = (const float*)d_in[14];

    float* out = (float*)d_out;
    float* emb = (float*)d_ws;   // Bn*Tn*En floats = 3.28 MB scratch

    k_emb<<<(Bn * Tn) / 4, 256, 0, stream>>>(src, W_res, W_gcn, b_gcn, emb);
    k_seq<<<Bn, 1024, 0, stream>>>(emb, src,
                                   W_ih_e, W_hh_e, b_e,
                                   W1, b1,
                                   W_ih_d, W_hh_d, b_d,
                                   W2, b2, out);
}

// Round 5
// 139.671 us; speedup vs baseline: 2.4343x; 2.4343x over previous
//
#include <hip/hip_runtime.h>

#define Bn 256
#define Nn 64
#define Tn 50
#define Fn 2
#define En 64
#define Hn 128
#define Rn 30
#define G4 512   // 4*H

typedef _Float16 h2 __attribute__((ext_vector_type(2)));

__device__ __forceinline__ float sigf(float x) {
    return __builtin_amdgcn_rcpf(1.0f + __expf(-x));
}
__device__ __forceinline__ float tanh_fast(float x) {
    return 1.0f - 2.0f * __builtin_amdgcn_rcpf(__expf(2.0f * x) + 1.0f);
}
__device__ __forceinline__ float dot2(h2 a, h2 b, float c) {
#if __has_builtin(__builtin_amdgcn_fdot2)
    return __builtin_amdgcn_fdot2(a, b, c, false);
#else
    return fmaf((float)a[0], (float)b[0], fmaf((float)a[1], (float)b[1], c));
#endif
}
__device__ __forceinline__ h2 pack2(float a, float b) {
    h2 r; r[0] = (_Float16)a; r[1] = (_Float16)b; return r;
}

// ---------------- Phase 1: emb[b*T+t, e] = relu(gcn + x@W_res) at node 0 ----------------
__global__ __launch_bounds__(256) void k_emb(const float* __restrict__ src,
                                             const float* __restrict__ W_res,
                                             const float* __restrict__ W_gcn,
                                             const float* __restrict__ b_gcn,
                                             float* __restrict__ emb)
{
    const int wave = threadIdx.x >> 6;
    const int lane = threadIdx.x & 63;
    const int task = blockIdx.x * 4 + wave;      // b*Tn + t
    const int b = task / Tn;
    const int t = task - b * Tn;

    __shared__ float2 xs[4][Nn];

    const float2 xv = *reinterpret_cast<const float2*>(
        src + (((size_t)b * Nn + lane) * Tn + t) * Fn);
    const float x0 = xv.x, x1 = xv.y;
    xs[wave][lane] = xv;
    __syncthreads();

    float rowsum = 0.0f, w0 = 0.0f;
    #pragma unroll
    for (int k = 0; k < Nn; k++) {
        const float2 o = xs[wave][k];
        const float dx = x0 - o.x, dy = x1 - o.y;
        const float w = fminf(__builtin_amdgcn_rsqf(dx * dx + dy * dy), 1.0f);
        rowsum += w;
        if (k == 0) w0 = w;
    }
    const float dinv  = __builtin_amdgcn_rsqf(rowsum);
    const float dinv0 = __shfl(dinv, 0);
    const float a = w0 * dinv0 * dinv;    // A[0, j]

    float p0 = a * x0, p1 = a * x1;
    #pragma unroll
    for (int off = 32; off; off >>= 1) {
        p0 += __shfl_xor(p0, off);
        p1 += __shfl_xor(p1, off);
    }
    const float xa = __shfl(x0, 0);
    const float xb = __shfl(x1, 0);

    const float v = p0 * W_gcn[lane] + p1 * W_gcn[En + lane] + b_gcn[lane]
                  + xa * W_res[lane] + xb * W_res[En + lane];
    emb[(size_t)task * En + lane] = fmaxf(v, 0.0f);
}

// ---------------- Phase 2+3: encoder (T) + decoder (R) LSTM ----------------
// 512 threads/block, 1 batch element/block. Thread (j2=(lane&15)+16*wv,
// s=lane>>4) computes partial gates for cell j2 over k-chunk [48s,48s+48).
// Weights held as 96 packed half2 VGPRs (fits the 128-VGPR budget the
// backend forces at 512 threads; R2-R4 showed fp32 weights spill and all
// budget-raising attributes are ignored). Gates via v_dot2_f32_f16 with
// fp32 accumulation; activations stored in LDS as half2 pairs.
__global__ __launch_bounds__(512) void k_seq(
    const float* __restrict__ emb,
    const float* __restrict__ src,
    const float* __restrict__ W_ih_e, const float* __restrict__ W_hh_e, const float* __restrict__ b_e,
    const float* __restrict__ W1,     const float* __restrict__ b1,
    const float* __restrict__ W_ih_d, const float* __restrict__ W_hh_d, const float* __restrict__ b_d,
    const float* __restrict__ W2,     const float* __restrict__ b2,
    float* __restrict__ out)
{
    const int tid  = threadIdx.x;
    const int lane = tid & 63;
    const int wv   = tid >> 6;                  // 0..7
    const int s    = lane >> 4;                 // 0..3
    const int j2   = (lane & 15) + (wv << 4);   // 0..127
    const int b    = blockIdx.x;

    // vbuf: half2 pairs; [0,32) = x (64 vals), [32,96) = h (128 vals)
    __shared__ __align__(16) h2 vbuf[2][96];
    __shared__ __align__(8) float red[8][2];

    h2 w[96];        // w[m*24+i] = (Wcat[48s+2i][j2+128m], Wcat[48s+2i+1][j2+128m])
    float bias[4];
    float c = 0.0f;

    // ---- encoder weights -> packed half2 VGPRs ----
    #pragma unroll
    for (int m = 0; m < 4; m++) {
        const int col = j2 + (m << 7);
        #pragma unroll
        for (int i = 0; i < 24; i++) {
            const int k = s * 48 + 2 * i;     // pairs never straddle the 64 boundary
            const float* p = (k < En) ? (W_ih_e + (size_t)k * G4 + col)
                                      : (W_hh_e + (size_t)(k - En) * G4 + col);
            unsigned int u = __builtin_bit_cast(unsigned int, pack2(p[0], p[G4]));
            asm volatile("" : "+v"(u));      // keep resident (prevent remat)
            w[m * 24 + i] = __builtin_bit_cast(h2, u);
        }
        bias[m] = b_e[col];
    }

    const float* emb_b = emb + (size_t)b * Tn * En;

    // init vbuf[0]: x from emb row 0, h = 0
    if (tid < 32) {
        const float2 e = *reinterpret_cast<const float2*>(emb_b + 2 * tid);
        vbuf[0][tid] = pack2(e.x, e.y);
    }
    if (tid >= 32 && tid < 96) vbuf[0][tid] = pack2(0.0f, 0.0f);
    __syncthreads();

    // ---- encoder: 50 steps, 1 barrier/step ----
    #pragma unroll 2
    for (int t = 0; t < Tn; t++) {
        const int cur = t & 1;
        float2 xnext;
        if (tid < 32 && t + 1 < Tn)
            xnext = *reinterpret_cast<const float2*>(emb_b + (t + 1) * En + 2 * tid);

        const float2* v2 = reinterpret_cast<const float2*>(&vbuf[cur][s * 24]);
        float a0 = 0.f, a1 = 0.f, a2 = 0.f, a3 = 0.f;
        #pragma unroll
        for (int i = 0; i < 12; i++) {
            const float2 u = v2[i];
            const h2 q0 = __builtin_bit_cast(h2, u.x);
            const h2 q1 = __builtin_bit_cast(h2, u.y);
            a0 = dot2(w[0*24+2*i], q0, a0); a0 = dot2(w[0*24+2*i+1], q1, a0);
            a1 = dot2(w[1*24+2*i], q0, a1); a1 = dot2(w[1*24+2*i+1], q1, a1);
            a2 = dot2(w[2*24+2*i], q0, a2); a2 = dot2(w[2*24+2*i+1], q1, a2);
            a3 = dot2(w[3*24+2*i], q0, a3); a3 = dot2(w[3*24+2*i+1], q1, a3);
        }
        a0 += __shfl_xor(a0, 16); a1 += __shfl_xor(a1, 16);
        a2 += __shfl_xor(a2, 16); a3 += __shfl_xor(a3, 16);
        a0 += __shfl_xor(a0, 32); a1 += __shfl_xor(a1, 32);
        a2 += __shfl_xor(a2, 32); a3 += __shfl_xor(a3, 32);

        const float gi = a0 + bias[0], gf = a1 + bias[1];
        const float gg = a2 + bias[2], go = a3 + bias[3];
        c = sigf(gf) * c + sigf(gi) * tanh_fast(gg);
        const float h = sigf(go) * tanh_fast(c);

        const float hp = __shfl_xor(h, 1);          // neighbor cell j2^1 (all lanes active)
        if (s == 0 && !(j2 & 1)) vbuf[cur ^ 1][32 + (j2 >> 1)] = pack2(h, hp);
        if (tid < 32 && t + 1 < Tn) vbuf[cur ^ 1][tid] = pack2(xnext.x, xnext.y);
        __syncthreads();
    }

    // ---- decoder weights -> same VGPRs ----
    #pragma unroll
    for (int m = 0; m < 4; m++) {
        const int col = j2 + (m << 7);
        #pragma unroll
        for (int i = 0; i < 24; i++) {
            const int k = s * 48 + 2 * i;
            const float* p = (k < En) ? (W_ih_d + (size_t)k * G4 + col)
                                      : (W_hh_d + (size_t)(k - En) * G4 + col);
            unsigned int u = __builtin_bit_cast(unsigned int, pack2(p[0], p[G4]));
            asm volatile("" : "+v"(u));
            w[m * 24 + i] = __builtin_bit_cast(h2, u);
        }
        bias[m] = b_d[col];
    }

    // wave-0 threads own output column tid (<64) for the ed = relu(xin@W1+b1) stage
    float w1a = 0.f, w1b = 0.f, b1v = 0.f;
    if (tid < En) { w1a = W1[tid]; w1b = W1[En + tid]; b1v = b1[tid]; }
    const float w2a = W2[2 * j2], w2b = W2[2 * j2 + 1];
    const float b20 = b2[0], b21 = b2[1];

    // prologue: ed from x[b, t=T-1, node 0]
    {
        const float xin0 = src[(size_t)b * Nn * Tn * Fn + (Tn - 1) * Fn + 0];
        const float xin1 = src[(size_t)b * Nn * Tn * Fn + (Tn - 1) * Fn + 1];
        if (tid < En) {       // whole wave 0 (uniform per wave -> shfl safe)
            const float e  = fmaxf(xin0 * w1a + xin1 * w1b + b1v, 0.0f);
            const float ep = __shfl_xor(e, 1);
            if (!(tid & 1)) vbuf[0][tid >> 1] = pack2(e, ep);
        }
    }
    __syncthreads();

    // ---- decoder: 30 steps, 2 barriers/step ----
    #pragma unroll 2
    for (int r = 0; r < Rn; r++) {
        const int cur = r & 1;
        const float2* v2 = reinterpret_cast<const float2*>(&vbuf[cur][s * 24]);
        float a0 = 0.f, a1 = 0.f, a2 = 0.f, a3 = 0.f;
        #pragma unroll
        for (int i = 0; i < 12; i++) {
            const float2 u = v2[i];
            const h2 q0 = __builtin_bit_cast(h2, u.x);
            const h2 q1 = __builtin_bit_cast(h2, u.y);
            a0 = dot2(w[0*24+2*i], q0, a0); a0 = dot2(w[0*24+2*i+1], q1, a0);
            a1 = dot2(w[1*24+2*i], q0, a1); a1 = dot2(w[1*24+2*i+1], q1, a1);
            a2 = dot2(w[2*24+2*i], q0, a2); a2 = dot2(w[2*24+2*i+1], q1, a2);
            a3 = dot2(w[3*24+2*i], q0, a3); a3 = dot2(w[3*24+2*i+1], q1, a3);
        }
        a0 += __shfl_xor(a0, 16); a1 += __shfl_xor(a1, 16);
        a2 += __shfl_xor(a2, 16); a3 += __shfl_xor(a3, 16);
        a0 += __shfl_xor(a0, 32); a1 += __shfl_xor(a1, 32);
        a2 += __shfl_xor(a2, 32); a3 += __shfl_xor(a3, 32);

        const float gi = a0 + bias[0], gf = a1 + bias[1];
        const float gg = a2 + bias[2], go = a3 + bias[3];
        c = sigf(gf) * c + sigf(gi) * tanh_fast(gg);
        const float h = sigf(go) * tanh_fast(c);

        const float hp = __shfl_xor(h, 1);
        if (s == 0 && !(j2 & 1)) vbuf[cur ^ 1][32 + (j2 >> 1)] = pack2(h, hp);

        // out = h @ W2 + b2 : per-wave butterfly on s==0 contributions
        float p0 = (s == 0) ? h * w2a : 0.0f;
        float p1 = (s == 0) ? h * w2b : 0.0f;
        #pragma unroll
        for (int off = 32; off; off >>= 1) {
            p0 += __shfl_xor(p0, off);
            p1 += __shfl_xor(p1, off);
        }
        if (lane == 0) { red[wv][0] = p0; red[wv][1] = p1; }
        __syncthreads();

        // finalize out + next ed (wave 0 only; redundant per-thread o0/o1)
        if (tid < En) {
            float o0 = b20, o1 = b21;
            #pragma unroll
            for (int k2 = 0; k2 < 8; k2++) {
                const float2 rr = *reinterpret_cast<const float2*>(&red[k2][0]);
                o0 += rr.x; o1 += rr.y;
            }
            if (tid == 0)
                *reinterpret_cast<float2*>(&out[((size_t)b * Rn + r) * Fn]) = make_float2(o0, o1);
            if (r + 1 < Rn) {
                const float e  = fmaxf(o0 * w1a + o1 * w1b + b1v, 0.0f);
                const float ep = __shfl_xor(e, 1);
                if (!(tid & 1)) vbuf[cur ^ 1][tid >> 1] = pack2(e, ep);
            }
        }
        __syncthreads();
    }
}

extern "C" void kernel_launch(void* const* d_in, const int* in_sizes, int n_in,
                              void* d_out, int out_size, void* d_ws, size_t ws_size,
                              hipStream_t stream)
{
    const float* src    = (const float*)d_in[0];
    const float* W_res  = (const float*)d_in[2];
    const float* W_gcn  = (const float*)d_in[3];
    const float* b_gcn  = (const float*)d_in[4];
    const float* W_ih_e = (const float*)d_in[5];
    const float* W_hh_e = (const float*)d_in[6];
    const float* b_e    = (const float*)d_in[7];
    const float* W1     = (const float*)d_in[8];
    const float* b1     = (const float*)d_in[9];
    const float* W_ih_d = (const float*)d_in[10];
    const float* W_hh_d = (const float*)d_in[11];
    const float* b_d    = (const float*)d_in[12];
    const float* W2     = (const float*)d_in[13];
    const float* b2     = (const float*)d_in[14];

    float* out = (float*)d_out;
    float* emb = (float*)d_ws;   // Bn*Tn*En floats = 3.28 MB scratch

    k_emb<<<(Bn * Tn) / 4, 256, 0, stream>>>(src, W_res, W_gcn, b_gcn, emb);
    k_seq<<<Bn, 512, 0, stream>>>(emb, src,
                                  W_ih_e, W_hh_e, b_e,
                                  W1, b1,
                                  W_ih_d, W_hh_d, b_d,
                                  W2, b2, out);
}